// Round 1
// baseline (116.005 us; speedup 1.0000x reference)
//
#include <hip/hip_runtime.h>

// GaussianBlurND: depthwise 9x9 Gaussian blur (sigma=2) on [16,64,256,256] f32,
// with edge correction  out = blur(x) / blur(ones).
//
// Separable: f[i][j] = g[i]*g[j], g normalized to sum 1.
// Correction factorizes: w[y][x] = wy[y]*wx[x], wy[y] = sum of g taps in-bounds.
//
// One block per (n,c) plane: 256 threads, one image column per thread.
// Vertical 9-tap pass via rolling register window (each input row read exactly
// once from HBM, coalesced). 16 blurred rows staged in LDS (pitch 264 with
// zeroed 4-col pads -> branchless horizontal taps, no bank conflicts), then
// horizontal 9-tap pass + border division, coalesced stores.

#define HH 256
#define WW 256
#define CHUNK 16

// Normalized 1-D Gaussian taps, sigma=2, k=9 (g = exp(-(i-4)^2/8) / sum).
#define G0 0.02763055f
#define G1 0.06628225f
#define G2 0.12383154f
#define G3 0.18017382f
#define G4 0.20416361f

__global__ __launch_bounds__(256) void gauss_blur_kernel(
    const float* __restrict__ x, float* __restrict__ out)
{
    const float G[9] = {G0, G1, G2, G3, G4, G3, G2, G1, G0};

    const int plane = blockIdx.x;                 // n*C + c
    const float* __restrict__ src = x + (size_t)plane * (HH * WW);
    float* __restrict__ dst = out + (size_t)plane * (HH * WW);
    const int tx = threadIdx.x;                   // column 0..255

    __shared__ float lds[CHUNK][WW + 8];          // 16 x 264 floats = 16.9 KB

    // Zero the 4-column pads once (they are never written by the vertical pass).
    if (tx < CHUNK * 8) {
        const int rr = tx >> 3, c = tx & 7;
        lds[rr][(c < 4) ? c : (c + WW)] = 0.f;
    }

    // Horizontal edge weight for this column (≠1 only for tx<4 or tx>=252).
    float inv_wx = 1.f;
    if (tx < 4 || tx >= WW - 4) {
        float wx = 0.f;
        #pragma unroll
        for (int j = 0; j < 9; ++j) {
            const unsigned q = (unsigned)(tx + j - 4);
            if (q < WW) wx += G[j];
        }
        inv_wx = 1.f / wx;
    }

    // Rolling vertical window: win[i] = row (r_out + i - 4) of this column.
    float win[9];
    #pragma unroll
    for (int i = 0; i < 9; ++i) {
        const int r = i - 4;
        win[i] = (r >= 0) ? src[r * WW + tx] : 0.f;
    }

    for (int rb = 0; rb < HH; rb += CHUNK) {
        // ---- vertical 9-tap pass for rows rb .. rb+CHUNK-1 ----
        #pragma unroll
        for (int rr = 0; rr < CHUNK; ++rr) {
            float v = G[0] * win[0];
            #pragma unroll
            for (int i = 1; i < 9; ++i) v = fmaf(G[i], win[i], v);
            lds[rr][tx + 4] = v;
            #pragma unroll
            for (int i = 0; i < 8; ++i) win[i] = win[i + 1];
            const int nr = rb + rr + 5;
            win[8] = (nr < HH) ? src[nr * WW + tx] : 0.f;
        }
        __syncthreads();

        // ---- horizontal 9-tap pass + edge correction ----
        #pragma unroll
        for (int rr = 0; rr < CHUNK; ++rr) {
            const int r = rb + rr;
            float s = G[0] * lds[rr][tx];
            #pragma unroll
            for (int j = 1; j < 9; ++j) s = fmaf(G[j], lds[rr][tx + j], s);

            float inv_wy = 1.f;                   // block-uniform branch
            if (r < 4 || r >= HH - 4) {
                float wy = 0.f;
                #pragma unroll
                for (int i = 0; i < 9; ++i) {
                    const unsigned q = (unsigned)(r + i - 4);
                    if (q < HH) wy += G[i];
                }
                inv_wy = 1.f / wy;
            }
            dst[r * WW + tx] = s * inv_wx * inv_wy;
        }
        __syncthreads();
    }
}

extern "C" void kernel_launch(void* const* d_in, const int* in_sizes, int n_in,
                              void* d_out, int out_size, void* d_ws, size_t ws_size,
                              hipStream_t stream)
{
    const float* x = (const float*)d_in[0];
    float* out = (float*)d_out;
    const int nplanes = in_sizes[0] / (HH * WW);  // 16*64 = 1024
    gauss_blur_kernel<<<nplanes, 256, 0, stream>>>(x, out);
}